// Round 9
// baseline (331.986 us; speedup 1.0000x reference)
//
#include <hip/hip_runtime.h>

typedef __bf16 bf16_t;
typedef __attribute__((ext_vector_type(4))) __bf16 bf16x4;
typedef __attribute__((ext_vector_type(8))) __bf16 bf16x8;
typedef __attribute__((ext_vector_type(4))) float f32x4;

#define MFMA_BF16(a, b, c) __builtin_amdgcn_mfma_f32_16x16x32_bf16((a), (b), (c), 0, 0, 0)

namespace {

constexpr int PIMG  = 5;
constexpr int TTOK  = 576;
constexpr int CCH   = 1280;
constexpr int NSEL  = 288;
constexpr int NH    = 20;
constexpr int ROWS  = 2 * PIMG * TTOK;     // 5760
constexpr int TKEYS = 4 * NSEL + TTOK;     // 1728
constexpr int KT_TILES = TKEYS / 64;       // 27
constexpr size_t NXE = (size_t)ROWS * CCH;   // 7372800
constexpr size_t NWE = (size_t)CCH * CCH;    // 1638400

__device__ __forceinline__ bf16x8 cvt8(const float* p) {
  const float4 f0 = *(const float4*)p;
  const float4 f1 = *(const float4*)(p + 4);
  bf16x8 r;
  r[0] = (bf16_t)f0.x; r[1] = (bf16_t)f0.y; r[2] = (bf16_t)f0.z; r[3] = (bf16_t)f0.w;
  r[4] = (bf16_t)f1.x; r[5] = (bf16_t)f1.y; r[6] = (bf16_t)f1.z; r[7] = (bf16_t)f1.w;
  return r;
}

// direct global->LDS async copy, 16 B per lane (m97 recipe).
__device__ __forceinline__ void gld_lds16(const bf16_t* g, bf16_t* l) {
  __builtin_amdgcn_global_load_lds(
      (const __attribute__((address_space(1))) unsigned int*)g,
      (__attribute__((address_space(3))) unsigned int*)l, 16, 0, 0);
}

// ---- one-shot f32 -> bf16 conversion of X and the 4 weight matrices ----
__global__ __launch_bounds__(256) void cvt_kernel(
    const float* __restrict__ X, const float* __restrict__ W0, const float* __restrict__ W1,
    const float* __restrict__ W2, const float* __restrict__ W3,
    bf16_t* __restrict__ Xb, bf16_t* __restrict__ Wb0, bf16_t* __restrict__ Wb1,
    bf16_t* __restrict__ Wb2, bf16_t* __restrict__ Wb3) {
  const int y = blockIdx.y;
  const float* src = y == 0 ? X : (y == 1 ? W0 : (y == 2 ? W1 : (y == 3 ? W2 : W3)));
  bf16_t* dst = y == 0 ? Xb : (y == 1 ? Wb0 : (y == 2 ? Wb1 : (y == 3 ? Wb2 : Wb3)));
  const size_t n = y == 0 ? NXE : NWE;
  const size_t idx = ((size_t)blockIdx.x * 256 + threadIdx.x) * 8;
  if (idx < n) *(bf16x8*)&dst[idx] = cvt8(&src[idx]);
}

// NT GEMM: C[m][n] = sum_k A[m][k]*B[n][k] (+bias) (*scale), bf16 in, fp32 acc.
// m97-style staging (global_load_lds w=16, linear [128][64] LDS). R7 measured
// this NEUTRAL vs reg-staged at this shape (K=1280); kept for lower VGPR.
template <bool BIAS, typename CT>
__device__ __forceinline__ void gemm_nt_body(const bf16_t* __restrict__ A,
                                             const bf16_t* __restrict__ B,
                                             const float* __restrict__ bias,
                                             CT* __restrict__ C,
                                             int bm, int bn, float scale) {
  __shared__ bf16_t As[128 * 64];
  __shared__ bf16_t Bs[128 * 64];

  const int tid  = threadIdx.x;
  const int lane = tid & 63;
  const int wave = tid >> 6;
  const int quad = lane >> 4;
  const int l16  = lane & 15;
  const int wr   = (wave >> 1) * 64;
  const int wc   = (wave & 1) * 64;
  const int m0   = bm * 128;
  const int n0   = bn * 128;

  const int srow = (lane >> 3);        // 0..7
  const int scol = (lane & 7) * 8;     // element offset of the 16B chunk

  f32x4 acc[4][4];
#pragma unroll
  for (int i = 0; i < 4; ++i)
#pragma unroll
    for (int j = 0; j < 4; ++j) acc[i][j] = (f32x4){0.f, 0.f, 0.f, 0.f};

  for (int it = 0; it < CCH / 64; ++it) {
    const int k0 = it * 64;
#pragma unroll
    for (int j = 0; j < 4; ++j) {
      const int r = 32 * wave + 8 * j + srow;
      gld_lds16(&A[(size_t)(m0 + r) * CCH + k0 + scol], &As[(32 * wave + 8 * j) * 64]);
      gld_lds16(&B[(size_t)(n0 + r) * CCH + k0 + scol], &Bs[(32 * wave + 8 * j) * 64]);
    }
    __syncthreads();  // vmcnt(0)+barrier: tiles resident
#pragma unroll
    for (int ks = 0; ks < 2; ++ks) {
      bf16x8 af[4], bfr[4];
#pragma unroll
      for (int i = 0; i < 4; ++i)
        af[i] = *(const bf16x8*)&As[(wr + 16 * i + l16) * 64 + ks * 32 + quad * 8];
#pragma unroll
      for (int j = 0; j < 4; ++j)
        bfr[j] = *(const bf16x8*)&Bs[(wc + 16 * j + l16) * 64 + ks * 32 + quad * 8];
#pragma unroll
      for (int i = 0; i < 4; ++i)
#pragma unroll
        for (int j = 0; j < 4; ++j)
          acc[i][j] = MFMA_BF16(af[i], bfr[j], acc[i][j]);
    }
    if (it < CCH / 64 - 1) __syncthreads();  // protect LDS from next staging
  }

  // epilogue: C/D layout col = l16, row = quad*4 + r
#pragma unroll
  for (int j = 0; j < 4; ++j) {
    const int col = n0 + wc + 16 * j + l16;
    const float bv = BIAS ? bias[col] : 0.f;
#pragma unroll
    for (int i = 0; i < 4; ++i) {
#pragma unroll
      for (int r = 0; r < 4; ++r) {
        const int row = m0 + wr + 16 * i + quad * 4 + r;
        const float val = acc[i][j][r] * scale + bv;
        if constexpr (sizeof(CT) == 2)
          C[(size_t)row * CCH + col] = (CT)val;
        else
          C[(size_t)row * CCH + col] = val;
      }
    }
  }
}

__global__ __launch_bounds__(256, 3) void qkv_gemm_kernel(
    const bf16_t* __restrict__ Xb,
    const bf16_t* __restrict__ Wqb, const bf16_t* __restrict__ Wkb, const bf16_t* __restrict__ Wvb,
    bf16_t* __restrict__ Qf, bf16_t* __restrict__ Kf, bf16_t* __restrict__ Vf) {
  const bf16_t* W = blockIdx.z == 0 ? Wqb : (blockIdx.z == 1 ? Wkb : Wvb);
  bf16_t* O = blockIdx.z == 0 ? Qf : (blockIdx.z == 1 ? Kf : Vf);
  // fold 1/sqrt(64) AND log2(e) into Q so attn softmax can use exp2 directly:
  // exp2(S*log2e) == exp(S). Error-neutral (same relative bf16 error, same
  // absolute exponent error) — R8's failure was the inline-asm exp, not this.
  const float scl = blockIdx.z == 0 ? 0.18033688011112042f : 1.0f;
  gemm_nt_body<false, bf16_t>(Xb, W, nullptr, O, blockIdx.x, blockIdx.y, scl);
}

__global__ __launch_bounds__(256, 3) void out_gemm_kernel(
    const bf16_t* __restrict__ Of, const bf16_t* __restrict__ Wob,
    const float* __restrict__ bo, float* __restrict__ out) {
  gemm_nt_body<true, float>(Of, Wob, bo, out, blockIdx.x, blockIdx.y, 1.0f);
}

// Flash attention over gathered K/V rows. R6 structure (95.5 µs).
// R9: R8's raw `asm(v_exp_f32)` produced stale-register reads — v_exp is a
// TRANS op with a required wait-state before result consumption; the hazard
// recognizer can't see producers inside opaque inline asm, so no s_nop was
// inserted (absmax 4.9e-4 -> 4.1e-3). Fix: exp2f() builtin (same single
// v_exp_f32, hazards handled). LESSON: never hand-write single-instruction
// transcendentals in asm. Split into 2 dispatches kept (diagnostic: lets
// qkv_gemm surface in the profiler top-5 if it is >= ~50 µs).
__global__ __launch_bounds__(128, 2) void attn_kernel(
    const bf16_t* __restrict__ Qf, const bf16_t* __restrict__ Kf, const bf16_t* __restrict__ Vf,
    const int* __restrict__ indices, bf16_t* __restrict__ Ofull, int bofs) {
  __shared__ unsigned short kvrow[TKEYS];        // 3456 B; dead after loop -> lred/linv
  __shared__ __align__(16) bf16_t Vts[2][64 * 64];  // 16 KB dbuf; dead after loop -> Osc

  const int tid  = threadIdx.x;
  const int lane = tid & 63;
  const int wave = tid >> 6;     // 0..1
  const int quad = lane >> 4;
  const int l16  = lane & 15;

  // XCD swizzle: b%8 = XCD (round-robin dispatch heuristic; speed-only)
  const int b   = blockIdx.x + bofs;
  const int xcd = b & 7;
  const int t   = b >> 3;            // 0..224
  const int gi  = t / 9;
  const int qt  = t - gi * 9;        // sibling index = q-tile
  const int g   = xcd + 8 * gi;      // 0..199 group id
  const int h   = g % NH;
  const int si  = g / NH;            // s*5 + i
  const int s   = si / PIMG;
  const int ii  = si % PIMG;

  const int r0 = si * TTOK + qt * 64;
  const int hc = h * 64;

  // Q B-frags, all 64 q, loop-invariant: aq[n][h2] -> B[q=16n+l16][d=quad*8+j+32*h2]
  bf16x8 aq[4][2];
#pragma unroll
  for (int n = 0; n < 4; ++n)
#pragma unroll
    for (int h2 = 0; h2 < 2; ++h2)
      aq[n][h2] = *(const bf16x8*)&Qf[(size_t)(r0 + 16 * n + l16) * CCH + hc + quad * 8 + 32 * h2];

  // key order: for p != ii ascending: gathered[p][0..287]; then own tokens 0..575
  for (int j = tid; j < TKEYS; j += 128) {
    int row;
    if (j < 4 * NSEL) {
      const int jp = j / NSEL;
      const int jj = j - jp * NSEL;
      const int p  = jp + (jp >= ii ? 1 : 0);
      row = (s * PIMG + p) * TTOK + indices[p * NSEL + jj];
    } else {
      row = si * TTOK + (j - 4 * NSEL);
    }
    kvrow[j] = (unsigned short)row;
  }
  __syncthreads();  // kvrow ready

  // K slot permutation: slot(kg) = 32w + 8*(l16>>2) + 4*kg + (l16&3).
  // QK^T output element (kg,quad,r) = key 32w+8*quad+4*kg+r == PV A-frag
  // elem j = 4*kg+r at k = 8*quad+j. P stays in registers.
  const int kidx = 32 * wave + ((l16 >> 2) << 3) + (l16 & 3);

  const int va = tid >> 3;        // 0..15: stages rows 4va..4va+3 (pairs 2va,2va+1)
  const int vc = (tid & 7) * 8;   // dim chunk

  bf16x8 kq[2][2], kn[2][2], vs[4], vn[4];
#pragma unroll
  for (int kg = 0; kg < 2; ++kg) {
    const int krow = kvrow[kidx + 4 * kg];
    kq[kg][0] = *(const bf16x8*)&Kf[(size_t)krow * CCH + hc + quad * 8];
    kq[kg][1] = *(const bf16x8*)&Kf[(size_t)krow * CCH + hc + quad * 8 + 32];
  }
#pragma unroll
  for (int e = 0; e < 4; ++e)
    vs[e] = *(const bf16x8*)&Vf[(size_t)kvrow[4 * va + e] * CCH + hc + vc];

  float l_part[4] = {0.f, 0.f, 0.f, 0.f};
  f32x4 oacc[4][4];
#pragma unroll
  for (int n = 0; n < 4; ++n)
#pragma unroll
    for (int dg = 0; dg < 4; ++dg) oacc[n][dg] = (f32x4){0.f, 0.f, 0.f, 0.f};

  for (int kt = 0; kt < KT_TILES; ++kt) {
    // ---- commit staged V tile: key-pairs packed as dwords, swizzled ----
    {
      unsigned int* V32 = (unsigned int*)&Vts[kt & 1][0];
      const unsigned short* q0 = (const unsigned short*)&vs[0];
      const unsigned short* q1 = (const unsigned short*)&vs[1];
      const unsigned short* q2 = (const unsigned short*)&vs[2];
      const unsigned short* q3 = (const unsigned short*)&vs[3];
#pragma unroll
      for (int x = 0; x < 8; ++x) {
        const int sx = (vc >> 1) ^ (x << 2);   // 4*(c^x)
        V32[(vc + x) * 32 + ((2 * va) ^ sx)]     = (unsigned int)q0[x] | ((unsigned int)q1[x] << 16);
        V32[(vc + x) * 32 + ((2 * va + 1) ^ sx)] = (unsigned int)q2[x] | ((unsigned int)q3[x] << 16);
      }
    }

    // ---- prefetch tile kt+1 (x1 across block, one iteration of slack) ----
    if (kt + 1 < KT_TILES) {
      const int kb = (kt + 1) * 64;
#pragma unroll
      for (int kg = 0; kg < 2; ++kg) {
        const int krow = kvrow[kb + kidx + 4 * kg];
        kn[kg][0] = *(const bf16x8*)&Kf[(size_t)krow * CCH + hc + quad * 8];
        kn[kg][1] = *(const bf16x8*)&Kf[(size_t)krow * CCH + hc + quad * 8 + 32];
      }
#pragma unroll
      for (int e = 0; e < 4; ++e)
        vn[e] = *(const bf16x8*)&Vf[(size_t)kvrow[kb + 4 * va + e] * CCH + hc + vc];
    }

    // ---- S^T = K Q^T (wave's 32 keys x all 64 q) + softmax into A-frags ----
    bf16x8 pa[4];
#pragma unroll
    for (int kg = 0; kg < 2; ++kg) {
#pragma unroll
      for (int n = 0; n < 4; ++n) {
        f32x4 z = (f32x4){0.f, 0.f, 0.f, 0.f};
        z = MFMA_BF16(kq[kg][0], aq[n][0], z);
        z = MFMA_BF16(kq[kg][1], aq[n][1], z);
#pragma unroll
        for (int r = 0; r < 4; ++r) {
          // exp2f -> single v_exp_f32 with compiler-managed TRANS hazards;
          // log2e pre-folded into Q scale, so exp2(z) == exp(S).
          const float pv = exp2f(z[r]);
          l_part[n] += pv;
          pa[n][4 * kg + r] = (bf16_t)pv;
        }
      }
    }

    __syncthreads();  // Vts[kt&1] visible (the ONLY barrier per iteration)

    // ---- O_partial[all 64 q][all 64 d] += P(wave keys) V(wave keys) ----
    const bf16_t* __restrict__ Vb = &Vts[kt & 1][0];
#pragma unroll
    for (int dg = 0; dg < 4; ++dg) {
      const int d  = 16 * dg + l16;
      const int sw = (d & 56) ^ ((d & 7) << 3);
      const bf16x8 vf = *(const bf16x8*)&Vb[d * 64 + ((32 * wave + 8 * quad) ^ sw)];
#pragma unroll
      for (int n = 0; n < 4; ++n)
        oacc[n][dg] = MFMA_BF16(pa[n], vf, oacc[n][dg]);
    }

    // rotate prefetched registers
#pragma unroll
    for (int kg = 0; kg < 2; ++kg) {
      kq[kg][0] = kn[kg][0];
      kq[kg][1] = kn[kg][1];
    }
#pragma unroll
    for (int e = 0; e < 4; ++e) vs[e] = vn[e];
  }

  __syncthreads();  // drain before aliasing kvrow/Vts as scratch

  // ---- merge l partials: 8 per q (2 waves x 4 quads) ----
  float* lred = (float*)kvrow;        // 512 f32 = 2048 B <= 3456
  float* linv = lred + 512;           // 64 f32
#pragma unroll
  for (int n = 0; n < 4; ++n)
    lred[(16 * n + l16) * 8 + 4 * wave + quad] = l_part[n];
  __syncthreads();
  if (tid < 64) {
    float tt = 0.f;
#pragma unroll
    for (int i = 0; i < 8; ++i) tt += lred[tid * 8 + i];
    linv[tid] = 1.f / tt;
  }
  __syncthreads();

  // ---- cross-wave O sum (f32 through dead Vts) + scaled write ----
  float* Osc = (float*)&Vts[0][0];    // 64*64 f32 = 16384 B (exact fit)
  if (wave == 0) {
#pragma unroll
    for (int n = 0; n < 4; ++n)
#pragma unroll
      for (int r = 0; r < 4; ++r) {
        const int q = 16 * n + 4 * quad + r;
#pragma unroll
        for (int dg = 0; dg < 4; ++dg)
          Osc[q * 64 + 16 * dg + l16] = oacc[n][dg][r];
      }
  }
  __syncthreads();
  if (wave == 1) {
#pragma unroll
    for (int n = 0; n < 4; ++n)
#pragma unroll
      for (int r = 0; r < 4; ++r) {
        const int q   = 16 * n + 4 * quad + r;
        const float inv = linv[q];
#pragma unroll
        for (int dg = 0; dg < 4; ++dg) {
          const float val = (Osc[q * 64 + 16 * dg + l16] + oacc[n][dg][r]) * inv;
          Ofull[(size_t)(r0 + q) * CCH + hc + 16 * dg + l16] = (bf16_t)val;
        }
      }
  }
}

}  // namespace

extern "C" void kernel_launch(void* const* d_in, const int* in_sizes, int n_in,
                              void* d_out, int out_size, void* d_ws, size_t ws_size,
                              hipStream_t stream) {
  const float* hs = (const float*)d_in[0];
  const float* Wq = (const float*)d_in[1];
  const float* Wk = (const float*)d_in[2];
  const float* Wv = (const float*)d_in[3];
  const float* Wo = (const float*)d_in[4];
  const float* bo = (const float*)d_in[5];
  const int* indices = (const int*)d_in[6];
  float* out = (float*)d_out;

  // ws layout (bf16): Qf, Kf, Vf, Xb(->Of after qkv gemm), Wqb, Wkb, Wvb, Wob = 72.1 MB
  bf16_t* Qf  = (bf16_t*)d_ws;
  bf16_t* Kf  = Qf + NXE;
  bf16_t* Vf  = Kf + NXE;
  bf16_t* Xb  = Vf + NXE;     // dead after qkv gemm
  bf16_t* Of  = Xb;           // attn output reuses the slot
  bf16_t* Wqb = Xb + NXE;
  bf16_t* Wkb = Wqb + NWE;
  bf16_t* Wvb = Wkb + NWE;
  bf16_t* Wob = Wvb + NWE;

  dim3 g0((NXE + 2047) / 2048, 5);
  cvt_kernel<<<g0, dim3(256), 0, stream>>>(hs, Wq, Wk, Wv, Wo, Xb, Wqb, Wkb, Wvb, Wob);

  dim3 g1(ROWS / 128, CCH / 128, 3);
  qkv_gemm_kernel<<<g1, dim3(256), 0, stream>>>(Xb, Wqb, Wkb, Wvb, Qf, Kf, Vf);

  // split attn: two 900-block dispatches so qkv_gemm can surface in the
  // profiler's top-5 (diagnostic fork for the flat ~200 µs non-attn time).
  attn_kernel<<<dim3(900), dim3(128), 0, stream>>>(Qf, Kf, Vf, indices, Of, 0);
  attn_kernel<<<dim3(900), dim3(128), 0, stream>>>(Qf, Kf, Vf, indices, Of, 900);

  dim3 g3(ROWS / 128, CCH / 128, 1);
  out_gemm_kernel<<<g3, dim3(256), 0, stream>>>(Of, Wob, bo, out);
}

// Round 10
// 319.643 us; speedup vs baseline: 1.0386x; 1.0386x over previous
//
#include <hip/hip_runtime.h>

typedef __bf16 bf16_t;
typedef __attribute__((ext_vector_type(4))) __bf16 bf16x4;
typedef __attribute__((ext_vector_type(8))) __bf16 bf16x8;
typedef __attribute__((ext_vector_type(4))) float f32x4;

#define MFMA_BF16(a, b, c) __builtin_amdgcn_mfma_f32_16x16x32_bf16((a), (b), (c), 0, 0, 0)

namespace {

constexpr int PIMG  = 5;
constexpr int TTOK  = 576;
constexpr int CCH   = 1280;
constexpr int NSEL  = 288;
constexpr int NH    = 20;
constexpr int ROWS  = 2 * PIMG * TTOK;     // 5760
constexpr int TKEYS = 4 * NSEL + TTOK;     // 1728
constexpr int KT_TILES = TKEYS / 64;       // 27
constexpr size_t NXE = (size_t)ROWS * CCH;   // 7372800
constexpr size_t NWE = (size_t)CCH * CCH;    // 1638400

__device__ __forceinline__ bf16x8 cvt8(const float* p) {
  const float4 f0 = *(const float4*)p;
  const float4 f1 = *(const float4*)(p + 4);
  bf16x8 r;
  r[0] = (bf16_t)f0.x; r[1] = (bf16_t)f0.y; r[2] = (bf16_t)f0.z; r[3] = (bf16_t)f0.w;
  r[4] = (bf16_t)f1.x; r[5] = (bf16_t)f1.y; r[6] = (bf16_t)f1.z; r[7] = (bf16_t)f1.w;
  return r;
}

// direct global->LDS async copy, 16 B per lane (m97 recipe).
__device__ __forceinline__ void gld_lds16(const bf16_t* g, bf16_t* l) {
  __builtin_amdgcn_global_load_lds(
      (const __attribute__((address_space(1))) unsigned int*)g,
      (__attribute__((address_space(3))) unsigned int*)l, 16, 0, 0);
}

// m204 bijective chunked XCD swizzle: blocks with the same blockIdx%8 (one
// XCD under round-robin dispatch) get CONTIGUOUS work ids -> the chunk's
// shared A/B panels become XCD-local L2 hits. Valid for nwg % 8 != 0.
template <int NWG>
__device__ __forceinline__ int xcd_chunk(int lin) {
  constexpr int q = NWG / 8, r = NWG % 8;
  const int xcd = lin & 7, idx = lin >> 3;
  return (xcd < r) ? xcd * (q + 1) + idx : r * (q + 1) + (xcd - r) * q + idx;
}

// ---- one-shot f32 -> bf16 conversion of X and the 4 weight matrices ----
__global__ __launch_bounds__(256) void cvt_kernel(
    const float* __restrict__ X, const float* __restrict__ W0, const float* __restrict__ W1,
    const float* __restrict__ W2, const float* __restrict__ W3,
    bf16_t* __restrict__ Xb, bf16_t* __restrict__ Wb0, bf16_t* __restrict__ Wb1,
    bf16_t* __restrict__ Wb2, bf16_t* __restrict__ Wb3) {
  const int y = blockIdx.y;
  const float* src = y == 0 ? X : (y == 1 ? W0 : (y == 2 ? W1 : (y == 3 ? W2 : W3)));
  bf16_t* dst = y == 0 ? Xb : (y == 1 ? Wb0 : (y == 2 ? Wb1 : (y == 3 ? Wb2 : Wb3)));
  const size_t n = y == 0 ? NXE : NWE;
  const size_t idx = ((size_t)blockIdx.x * 256 + threadIdx.x) * 8;
  if (idx < n) *(bf16x8*)&dst[idx] = cvt8(&src[idx]);
}

// NT GEMM: C[m][n] = sum_k A[m][k]*B[n][k] (+bias) (*scale), bf16 in, fp32 acc.
// m97-style staging (global_load_lds w=16, linear [128][64] LDS).
// R10: R9 profiling showed qkv at 94 µs with FETCH 199 MB (8x overfetch:
// round-robin XCD placement makes the ~8 co-resident readers of each A-panel
// sit on different XCDs). Fixes: chunked XCD swizzle (caller) + lb(256,4)
// (VGPR 76 fits; 4x32KB LDS = 128 <= 160 KB) for one more resident block.
template <bool BIAS, typename CT>
__device__ __forceinline__ void gemm_nt_body(const bf16_t* __restrict__ A,
                                             const bf16_t* __restrict__ B,
                                             const float* __restrict__ bias,
                                             CT* __restrict__ C,
                                             int bm, int bn, float scale) {
  __shared__ bf16_t As[128 * 64];
  __shared__ bf16_t Bs[128 * 64];

  const int tid  = threadIdx.x;
  const int lane = tid & 63;
  const int wave = tid >> 6;
  const int quad = lane >> 4;
  const int l16  = lane & 15;
  const int wr   = (wave >> 1) * 64;
  const int wc   = (wave & 1) * 64;
  const int m0   = bm * 128;
  const int n0   = bn * 128;

  const int srow = (lane >> 3);        // 0..7
  const int scol = (lane & 7) * 8;     // element offset of the 16B chunk

  f32x4 acc[4][4];
#pragma unroll
  for (int i = 0; i < 4; ++i)
#pragma unroll
    for (int j = 0; j < 4; ++j) acc[i][j] = (f32x4){0.f, 0.f, 0.f, 0.f};

  for (int it = 0; it < CCH / 64; ++it) {
    const int k0 = it * 64;
#pragma unroll
    for (int j = 0; j < 4; ++j) {
      const int r = 32 * wave + 8 * j + srow;
      gld_lds16(&A[(size_t)(m0 + r) * CCH + k0 + scol], &As[(32 * wave + 8 * j) * 64]);
      gld_lds16(&B[(size_t)(n0 + r) * CCH + k0 + scol], &Bs[(32 * wave + 8 * j) * 64]);
    }
    __syncthreads();  // vmcnt(0)+barrier: tiles resident
#pragma unroll
    for (int ks = 0; ks < 2; ++ks) {
      bf16x8 af[4], bfr[4];
#pragma unroll
      for (int i = 0; i < 4; ++i)
        af[i] = *(const bf16x8*)&As[(wr + 16 * i + l16) * 64 + ks * 32 + quad * 8];
#pragma unroll
      for (int j = 0; j < 4; ++j)
        bfr[j] = *(const bf16x8*)&Bs[(wc + 16 * j + l16) * 64 + ks * 32 + quad * 8];
#pragma unroll
      for (int i = 0; i < 4; ++i)
#pragma unroll
        for (int j = 0; j < 4; ++j)
          acc[i][j] = MFMA_BF16(af[i], bfr[j], acc[i][j]);
    }
    if (it < CCH / 64 - 1) __syncthreads();  // protect LDS from next staging
  }

  // epilogue: C/D layout col = l16, row = quad*4 + r
#pragma unroll
  for (int j = 0; j < 4; ++j) {
    const int col = n0 + wc + 16 * j + l16;
    const float bv = BIAS ? bias[col] : 0.f;
#pragma unroll
    for (int i = 0; i < 4; ++i) {
#pragma unroll
      for (int r = 0; r < 4; ++r) {
        const int row = m0 + wr + 16 * i + quad * 4 + r;
        const float val = acc[i][j][r] * scale + bv;
        if constexpr (sizeof(CT) == 2)
          C[(size_t)row * CCH + col] = (CT)val;
        else
          C[(size_t)row * CCH + col] = val;
      }
    }
  }
}

// 1D grid 1350 = 45 bm x 10 bn x 3 z, chunk-swizzled. bm fastest within a
// chunk (contiguous wgid = contiguous bm) so an XCD's resident blocks share
// B-panels and sweep A in-order.
__global__ __launch_bounds__(256, 4) void qkv_gemm_kernel(
    const bf16_t* __restrict__ Xb,
    const bf16_t* __restrict__ Wqb, const bf16_t* __restrict__ Wkb, const bf16_t* __restrict__ Wvb,
    bf16_t* __restrict__ Qf, bf16_t* __restrict__ Kf, bf16_t* __restrict__ Vf) {
  const int wgid = xcd_chunk<1350>(blockIdx.x);
  const int bm   = wgid % 45;
  const int rest = wgid / 45;        // 0..29
  const int bn   = rest % 10;
  const int z    = rest / 10;        // 0..2
  const bf16_t* W = z == 0 ? Wqb : (z == 1 ? Wkb : Wvb);
  bf16_t* O = z == 0 ? Qf : (z == 1 ? Kf : Vf);
  // fold 1/sqrt(64) AND log2(e) into Q so attn softmax can use exp2 directly.
  const float scl = z == 0 ? 0.18033688011112042f : 1.0f;
  gemm_nt_body<false, bf16_t>(Xb, W, nullptr, O, bm, bn, scl);
}

__global__ __launch_bounds__(256, 4) void out_gemm_kernel(
    const bf16_t* __restrict__ Of, const bf16_t* __restrict__ Wob,
    const float* __restrict__ bo, float* __restrict__ out) {
  const int wgid = xcd_chunk<450>(blockIdx.x);
  gemm_nt_body<true, float>(Of, Wob, bo, out, wgid % 45, wgid / 45, 1.0f);
}

// Flash attention over gathered K/V rows. R6 structure (95.5 µs), single 1800
// dispatch restored (R9's split cost ~20 µs of dispatch tails; diagnostic
// complete). exp2f + log2e-folded Q scale kept (R9 passed, absmax 4.9e-4).
__global__ __launch_bounds__(128, 2) void attn_kernel(
    const bf16_t* __restrict__ Qf, const bf16_t* __restrict__ Kf, const bf16_t* __restrict__ Vf,
    const int* __restrict__ indices, bf16_t* __restrict__ Ofull) {
  __shared__ unsigned short kvrow[TKEYS];        // 3456 B; dead after loop -> lred/linv
  __shared__ __align__(16) bf16_t Vts[2][64 * 64];  // 16 KB dbuf; dead after loop -> Osc

  const int tid  = threadIdx.x;
  const int lane = tid & 63;
  const int wave = tid >> 6;     // 0..1
  const int quad = lane >> 4;
  const int l16  = lane & 15;

  // XCD swizzle: b%8 = XCD (round-robin dispatch heuristic; speed-only)
  const int b   = blockIdx.x;
  const int xcd = b & 7;
  const int t   = b >> 3;            // 0..224
  const int gi  = t / 9;
  const int qt  = t - gi * 9;        // sibling index = q-tile
  const int g   = xcd + 8 * gi;      // 0..199 group id
  const int h   = g % NH;
  const int si  = g / NH;            // s*5 + i
  const int s   = si / PIMG;
  const int ii  = si % PIMG;

  const int r0 = si * TTOK + qt * 64;
  const int hc = h * 64;

  // Q B-frags, all 64 q, loop-invariant: aq[n][h2] -> B[q=16n+l16][d=quad*8+j+32*h2]
  bf16x8 aq[4][2];
#pragma unroll
  for (int n = 0; n < 4; ++n)
#pragma unroll
    for (int h2 = 0; h2 < 2; ++h2)
      aq[n][h2] = *(const bf16x8*)&Qf[(size_t)(r0 + 16 * n + l16) * CCH + hc + quad * 8 + 32 * h2];

  // key order: for p != ii ascending: gathered[p][0..287]; then own tokens 0..575
  for (int j = tid; j < TKEYS; j += 128) {
    int row;
    if (j < 4 * NSEL) {
      const int jp = j / NSEL;
      const int jj = j - jp * NSEL;
      const int p  = jp + (jp >= ii ? 1 : 0);
      row = (s * PIMG + p) * TTOK + indices[p * NSEL + jj];
    } else {
      row = si * TTOK + (j - 4 * NSEL);
    }
    kvrow[j] = (unsigned short)row;
  }
  __syncthreads();  // kvrow ready

  // K slot permutation: slot(kg) = 32w + 8*(l16>>2) + 4*kg + (l16&3).
  // QK^T output element (kg,quad,r) = key 32w+8*quad+4*kg+r == PV A-frag
  // elem j = 4*kg+r at k = 8*quad+j. P stays in registers.
  const int kidx = 32 * wave + ((l16 >> 2) << 3) + (l16 & 3);

  const int va = tid >> 3;        // 0..15: stages rows 4va..4va+3 (pairs 2va,2va+1)
  const int vc = (tid & 7) * 8;   // dim chunk

  bf16x8 kq[2][2], kn[2][2], vs[4], vn[4];
#pragma unroll
  for (int kg = 0; kg < 2; ++kg) {
    const int krow = kvrow[kidx + 4 * kg];
    kq[kg][0] = *(const bf16x8*)&Kf[(size_t)krow * CCH + hc + quad * 8];
    kq[kg][1] = *(const bf16x8*)&Kf[(size_t)krow * CCH + hc + quad * 8 + 32];
  }
#pragma unroll
  for (int e = 0; e < 4; ++e)
    vs[e] = *(const bf16x8*)&Vf[(size_t)kvrow[4 * va + e] * CCH + hc + vc];

  float l_part[4] = {0.f, 0.f, 0.f, 0.f};
  f32x4 oacc[4][4];
#pragma unroll
  for (int n = 0; n < 4; ++n)
#pragma unroll
    for (int dg = 0; dg < 4; ++dg) oacc[n][dg] = (f32x4){0.f, 0.f, 0.f, 0.f};

  for (int kt = 0; kt < KT_TILES; ++kt) {
    // ---- commit staged V tile: key-pairs packed as dwords, swizzled ----
    {
      unsigned int* V32 = (unsigned int*)&Vts[kt & 1][0];
      const unsigned short* q0 = (const unsigned short*)&vs[0];
      const unsigned short* q1 = (const unsigned short*)&vs[1];
      const unsigned short* q2 = (const unsigned short*)&vs[2];
      const unsigned short* q3 = (const unsigned short*)&vs[3];
#pragma unroll
      for (int x = 0; x < 8; ++x) {
        const int sx = (vc >> 1) ^ (x << 2);   // 4*(c^x)
        V32[(vc + x) * 32 + ((2 * va) ^ sx)]     = (unsigned int)q0[x] | ((unsigned int)q1[x] << 16);
        V32[(vc + x) * 32 + ((2 * va + 1) ^ sx)] = (unsigned int)q2[x] | ((unsigned int)q3[x] << 16);
      }
    }

    // ---- prefetch tile kt+1 (x1 across block, one iteration of slack) ----
    if (kt + 1 < KT_TILES) {
      const int kb = (kt + 1) * 64;
#pragma unroll
      for (int kg = 0; kg < 2; ++kg) {
        const int krow = kvrow[kb + kidx + 4 * kg];
        kn[kg][0] = *(const bf16x8*)&Kf[(size_t)krow * CCH + hc + quad * 8];
        kn[kg][1] = *(const bf16x8*)&Kf[(size_t)krow * CCH + hc + quad * 8 + 32];
      }
#pragma unroll
      for (int e = 0; e < 4; ++e)
        vn[e] = *(const bf16x8*)&Vf[(size_t)kvrow[kb + 4 * va + e] * CCH + hc + vc];
    }

    // ---- S^T = K Q^T (wave's 32 keys x all 64 q) + softmax into A-frags ----
    bf16x8 pa[4];
#pragma unroll
    for (int kg = 0; kg < 2; ++kg) {
#pragma unroll
      for (int n = 0; n < 4; ++n) {
        f32x4 z = (f32x4){0.f, 0.f, 0.f, 0.f};
        z = MFMA_BF16(kq[kg][0], aq[n][0], z);
        z = MFMA_BF16(kq[kg][1], aq[n][1], z);
#pragma unroll
        for (int r = 0; r < 4; ++r) {
          // exp2f -> single v_exp_f32 with compiler-managed TRANS hazards;
          // log2e pre-folded into Q scale, so exp2(z) == exp(S).
          const float pv = exp2f(z[r]);
          l_part[n] += pv;
          pa[n][4 * kg + r] = (bf16_t)pv;
        }
      }
    }

    __syncthreads();  // Vts[kt&1] visible (the ONLY barrier per iteration)

    // ---- O_partial[all 64 q][all 64 d] += P(wave keys) V(wave keys) ----
    const bf16_t* __restrict__ Vb = &Vts[kt & 1][0];
#pragma unroll
    for (int dg = 0; dg < 4; ++dg) {
      const int d  = 16 * dg + l16;
      const int sw = (d & 56) ^ ((d & 7) << 3);
      const bf16x8 vf = *(const bf16x8*)&Vb[d * 64 + ((32 * wave + 8 * quad) ^ sw)];
#pragma unroll
      for (int n = 0; n < 4; ++n)
        oacc[n][dg] = MFMA_BF16(pa[n], vf, oacc[n][dg]);
    }

    // rotate prefetched registers
#pragma unroll
    for (int kg = 0; kg < 2; ++kg) {
      kq[kg][0] = kn[kg][0];
      kq[kg][1] = kn[kg][1];
    }
#pragma unroll
    for (int e = 0; e < 4; ++e) vs[e] = vn[e];
  }

  __syncthreads();  // drain before aliasing kvrow/Vts as scratch

  // ---- merge l partials: 8 per q (2 waves x 4 quads) ----
  float* lred = (float*)kvrow;        // 512 f32 = 2048 B <= 3456
  float* linv = lred + 512;           // 64 f32
#pragma unroll
  for (int n = 0; n < 4; ++n)
    lred[(16 * n + l16) * 8 + 4 * wave + quad] = l_part[n];
  __syncthreads();
  if (tid < 64) {
    float tt = 0.f;
#pragma unroll
    for (int i = 0; i < 8; ++i) tt += lred[tid * 8 + i];
    linv[tid] = 1.f / tt;
  }
  __syncthreads();

  // ---- cross-wave O sum (f32 through dead Vts) + scaled write ----
  float* Osc = (float*)&Vts[0][0];    // 64*64 f32 = 16384 B (exact fit)
  if (wave == 0) {
#pragma unroll
    for (int n = 0; n < 4; ++n)
#pragma unroll
      for (int r = 0; r < 4; ++r) {
        const int q = 16 * n + 4 * quad + r;
#pragma unroll
        for (int dg = 0; dg < 4; ++dg)
          Osc[q * 64 + 16 * dg + l16] = oacc[n][dg][r];
      }
  }
  __syncthreads();
  if (wave == 1) {
#pragma unroll
    for (int n = 0; n < 4; ++n)
#pragma unroll
      for (int r = 0; r < 4; ++r) {
        const int q   = 16 * n + 4 * quad + r;
        const float inv = linv[q];
#pragma unroll
        for (int dg = 0; dg < 4; ++dg) {
          const float val = (Osc[q * 64 + 16 * dg + l16] + oacc[n][dg][r]) * inv;
          Ofull[(size_t)(r0 + q) * CCH + hc + 16 * dg + l16] = (bf16_t)val;
        }
      }
  }
}

}  // namespace

extern "C" void kernel_launch(void* const* d_in, const int* in_sizes, int n_in,
                              void* d_out, int out_size, void* d_ws, size_t ws_size,
                              hipStream_t stream) {
  const float* hs = (const float*)d_in[0];
  const float* Wq = (const float*)d_in[1];
  const float* Wk = (const float*)d_in[2];
  const float* Wv = (const float*)d_in[3];
  const float* Wo = (const float*)d_in[4];
  const float* bo = (const float*)d_in[5];
  const int* indices = (const int*)d_in[6];
  float* out = (float*)d_out;

  // ws layout (bf16): Qf, Kf, Vf, Xb(->Of after qkv gemm), Wqb, Wkb, Wvb, Wob = 72.1 MB
  bf16_t* Qf  = (bf16_t*)d_ws;
  bf16_t* Kf  = Qf + NXE;
  bf16_t* Vf  = Kf + NXE;
  bf16_t* Xb  = Vf + NXE;     // dead after qkv gemm
  bf16_t* Of  = Xb;           // attn output reuses the slot
  bf16_t* Wqb = Xb + NXE;
  bf16_t* Wkb = Wqb + NWE;
  bf16_t* Wvb = Wkb + NWE;
  bf16_t* Wob = Wvb + NWE;

  dim3 g0((NXE + 2047) / 2048, 5);
  cvt_kernel<<<g0, dim3(256), 0, stream>>>(hs, Wq, Wk, Wv, Wo, Xb, Wqb, Wkb, Wvb, Wob);

  // 1D chunk-swizzled grids (45 bm x 10 bn x {3,1} z decoded in-kernel)
  qkv_gemm_kernel<<<dim3(1350), dim3(256), 0, stream>>>(Xb, Wqb, Wkb, Wvb, Qf, Kf, Vf);

  attn_kernel<<<dim3(1800), dim3(128), 0, stream>>>(Qf, Kf, Vf, indices, Of);

  out_gemm_kernel<<<dim3(450), dim3(256), 0, stream>>>(Of, Wob, bo, out);
}

// Round 12
// 296.909 us; speedup vs baseline: 1.1181x; 1.0766x over previous
//
#include <hip/hip_runtime.h>

typedef __bf16 bf16_t;
typedef __attribute__((ext_vector_type(4))) __bf16 bf16x4;
typedef __attribute__((ext_vector_type(8))) __bf16 bf16x8;
typedef __attribute__((ext_vector_type(4))) float f32x4;

#define MFMA_BF16(a, b, c) __builtin_amdgcn_mfma_f32_16x16x32_bf16((a), (b), (c), 0, 0, 0)

namespace {

constexpr int PIMG  = 5;
constexpr int TTOK  = 576;
constexpr int CCH   = 1280;
constexpr int NSEL  = 288;
constexpr int NH    = 20;
constexpr int ROWS  = 2 * PIMG * TTOK;     // 5760
constexpr int TKEYS = 4 * NSEL + TTOK;     // 1728
constexpr int KT_TILES = TKEYS / 64;       // 27
constexpr size_t NXE = (size_t)ROWS * CCH;   // 7372800
constexpr size_t NWE = (size_t)CCH * CCH;    // 1638400

__device__ __forceinline__ bf16x8 cvt8(const float* p) {
  const float4 f0 = *(const float4*)p;
  const float4 f1 = *(const float4*)(p + 4);
  bf16x8 r;
  r[0] = (bf16_t)f0.x; r[1] = (bf16_t)f0.y; r[2] = (bf16_t)f0.z; r[3] = (bf16_t)f0.w;
  r[4] = (bf16_t)f1.x; r[5] = (bf16_t)f1.y; r[6] = (bf16_t)f1.z; r[7] = (bf16_t)f1.w;
  return r;
}

// direct global->LDS async copy, 16 B per lane (m97 recipe).
__device__ __forceinline__ void gld_lds16(const bf16_t* g, bf16_t* l) {
  __builtin_amdgcn_global_load_lds(
      (const __attribute__((address_space(1))) unsigned int*)g,
      (__attribute__((address_space(3))) unsigned int*)l, 16, 0, 0);
}

// m204 bijective chunked XCD swizzle: blocks with the same blockIdx%8 (one
// XCD under round-robin dispatch) get CONTIGUOUS work ids -> the chunk's
// shared A/B panels become XCD-local L2 hits. Valid for nwg % 8 != 0.
template <int NWG>
__device__ __forceinline__ int xcd_chunk(int lin) {
  constexpr int q = NWG / 8, r = NWG % 8;
  const int xcd = lin & 7, idx = lin >> 3;
  return (xcd < r) ? xcd * (q + 1) + idx : r * (q + 1) + (xcd - r) * q + idx;
}

// ---- one-shot f32 -> bf16 conversion of X and the 4 weight matrices ----
__global__ __launch_bounds__(256) void cvt_kernel(
    const float* __restrict__ X, const float* __restrict__ W0, const float* __restrict__ W1,
    const float* __restrict__ W2, const float* __restrict__ W3,
    bf16_t* __restrict__ Xb, bf16_t* __restrict__ Wb0, bf16_t* __restrict__ Wb1,
    bf16_t* __restrict__ Wb2, bf16_t* __restrict__ Wb3) {
  const int y = blockIdx.y;
  const float* src = y == 0 ? X : (y == 1 ? W0 : (y == 2 ? W1 : (y == 3 ? W2 : W3)));
  bf16_t* dst = y == 0 ? Xb : (y == 1 ? Wb0 : (y == 2 ? Wb1 : (y == 3 ? Wb2 : Wb3)));
  const size_t n = y == 0 ? NXE : NWE;
  const size_t idx = ((size_t)blockIdx.x * 256 + threadIdx.x) * 8;
  if (idx < n) *(bf16x8*)&dst[idx] = cvt8(&src[idx]);
}

// NT GEMM: C[m][n] = sum_k A[m][k]*B[n][k] (+bias) (*scale), bf16 in, fp32 acc.
// m97-style staging (global_load_lds w=16, linear [128][64] LDS) + chunked
// XCD swizzle (R10) + lb(256,4). FROZEN: R12's total attributes it vs R6.
template <bool BIAS, typename CT>
__device__ __forceinline__ void gemm_nt_body(const bf16_t* __restrict__ A,
                                             const bf16_t* __restrict__ B,
                                             const float* __restrict__ bias,
                                             CT* __restrict__ C,
                                             int bm, int bn, float scale) {
  __shared__ bf16_t As[128 * 64];
  __shared__ bf16_t Bs[128 * 64];

  const int tid  = threadIdx.x;
  const int lane = tid & 63;
  const int wave = tid >> 6;
  const int quad = lane >> 4;
  const int l16  = lane & 15;
  const int wr   = (wave >> 1) * 64;
  const int wc   = (wave & 1) * 64;
  const int m0   = bm * 128;
  const int n0   = bn * 128;

  const int srow = (lane >> 3);        // 0..7
  const int scol = (lane & 7) * 8;     // element offset of the 16B chunk

  f32x4 acc[4][4];
#pragma unroll
  for (int i = 0; i < 4; ++i)
#pragma unroll
    for (int j = 0; j < 4; ++j) acc[i][j] = (f32x4){0.f, 0.f, 0.f, 0.f};

  for (int it = 0; it < CCH / 64; ++it) {
    const int k0 = it * 64;
#pragma unroll
    for (int j = 0; j < 4; ++j) {
      const int r = 32 * wave + 8 * j + srow;
      gld_lds16(&A[(size_t)(m0 + r) * CCH + k0 + scol], &As[(32 * wave + 8 * j) * 64]);
      gld_lds16(&B[(size_t)(n0 + r) * CCH + k0 + scol], &Bs[(32 * wave + 8 * j) * 64]);
    }
    __syncthreads();  // vmcnt(0)+barrier: tiles resident
#pragma unroll
    for (int ks = 0; ks < 2; ++ks) {
      bf16x8 af[4], bfr[4];
#pragma unroll
      for (int i = 0; i < 4; ++i)
        af[i] = *(const bf16x8*)&As[(wr + 16 * i + l16) * 64 + ks * 32 + quad * 8];
#pragma unroll
      for (int j = 0; j < 4; ++j)
        bfr[j] = *(const bf16x8*)&Bs[(wc + 16 * j + l16) * 64 + ks * 32 + quad * 8];
#pragma unroll
      for (int i = 0; i < 4; ++i)
#pragma unroll
        for (int j = 0; j < 4; ++j)
          acc[i][j] = MFMA_BF16(af[i], bfr[j], acc[i][j]);
    }
    if (it < CCH / 64 - 1) __syncthreads();  // protect LDS from next staging
  }

  // epilogue: C/D layout col = l16, row = quad*4 + r
#pragma unroll
  for (int j = 0; j < 4; ++j) {
    const int col = n0 + wc + 16 * j + l16;
    const float bv = BIAS ? bias[col] : 0.f;
#pragma unroll
    for (int i = 0; i < 4; ++i) {
#pragma unroll
      for (int r = 0; r < 4; ++r) {
        const int row = m0 + wr + 16 * i + quad * 4 + r;
        const float val = acc[i][j][r] * scale + bv;
        if constexpr (sizeof(CT) == 2)
          C[(size_t)row * CCH + col] = (CT)val;
        else
          C[(size_t)row * CCH + col] = val;
      }
    }
  }
}

// 1D grid 1350 = 45 bm x 10 bn x 3 z, chunk-swizzled. bm fastest within a
// chunk (contiguous wgid = contiguous bm) so an XCD's resident blocks share
// B-panels and sweep A in-order.
__global__ __launch_bounds__(256, 4) void qkv_gemm_kernel(
    const bf16_t* __restrict__ Xb,
    const bf16_t* __restrict__ Wqb, const bf16_t* __restrict__ Wkb, const bf16_t* __restrict__ Wvb,
    bf16_t* __restrict__ Qf, bf16_t* __restrict__ Kf, bf16_t* __restrict__ Vf) {
  const int wgid = xcd_chunk<1350>(blockIdx.x);
  const int bm   = wgid % 45;
  const int rest = wgid / 45;        // 0..29
  const int bn   = rest % 10;
  const int z    = rest / 10;        // 0..2
  const bf16_t* W = z == 0 ? Wqb : (z == 1 ? Wkb : Wvb);
  bf16_t* O = z == 0 ? Qf : (z == 1 ? Kf : Vf);
  // fold 1/sqrt(64) AND log2(e) into Q so attn softmax can use exp2 directly.
  const float scl = z == 0 ? 0.18033688011112042f : 1.0f;
  gemm_nt_body<false, bf16_t>(Xb, W, nullptr, O, bm, bn, scl);
}

__global__ __launch_bounds__(256, 4) void out_gemm_kernel(
    const bf16_t* __restrict__ Of, const bf16_t* __restrict__ Wob,
    const float* __restrict__ bo, float* __restrict__ out) {
  const int wgid = xcd_chunk<450>(blockIdx.x);
  gemm_nt_body<true, float>(Of, Wob, bo, out, wgid % 45, wgid / 45, 1.0f);
}

// Flash attention over gathered K/V rows. R6 structure. R11/R12: fix R10's
// regression — exp2f() on ROCm is the PRECISE ocml exp2 (denorm/range fixup:
// extra cmp/cndmask/ldexp per call -> VGPR 116->128, VALUBusy 42->52, attn
// 95.5->119 µs). __builtin_amdgcn_exp2f is the raw v_exp_f32 with
// compiler-managed TRANS hazards (R8's opaque-asm stale-read cannot recur).
// Exp ladder lesson: __expf = v_mul+v_exp OK; exp2f = precise/slow; raw asm
// = hazard-broken; builtin = correct & minimal.
// (R11 bench was lost to a container-acquisition failure; resubmitted unchanged.)
__global__ __launch_bounds__(128, 2) void attn_kernel(
    const bf16_t* __restrict__ Qf, const bf16_t* __restrict__ Kf, const bf16_t* __restrict__ Vf,
    const int* __restrict__ indices, bf16_t* __restrict__ Ofull) {
  __shared__ unsigned short kvrow[TKEYS];        // 3456 B; dead after loop -> lred/linv
  __shared__ __align__(16) bf16_t Vts[2][64 * 64];  // 16 KB dbuf; dead after loop -> Osc

  const int tid  = threadIdx.x;
  const int lane = tid & 63;
  const int wave = tid >> 6;     // 0..1
  const int quad = lane >> 4;
  const int l16  = lane & 15;

  // XCD swizzle: b%8 = XCD (round-robin dispatch heuristic; speed-only)
  const int b   = blockIdx.x;
  const int xcd = b & 7;
  const int t   = b >> 3;            // 0..224
  const int gi  = t / 9;
  const int qt  = t - gi * 9;        // sibling index = q-tile
  const int g   = xcd + 8 * gi;      // 0..199 group id
  const int h   = g % NH;
  const int si  = g / NH;            // s*5 + i
  const int s   = si / PIMG;
  const int ii  = si % PIMG;

  const int r0 = si * TTOK + qt * 64;
  const int hc = h * 64;

  // Q B-frags, all 64 q, loop-invariant: aq[n][h2] -> B[q=16n+l16][d=quad*8+j+32*h2]
  bf16x8 aq[4][2];
#pragma unroll
  for (int n = 0; n < 4; ++n)
#pragma unroll
    for (int h2 = 0; h2 < 2; ++h2)
      aq[n][h2] = *(const bf16x8*)&Qf[(size_t)(r0 + 16 * n + l16) * CCH + hc + quad * 8 + 32 * h2];

  // key order: for p != ii ascending: gathered[p][0..287]; then own tokens 0..575
  for (int j = tid; j < TKEYS; j += 128) {
    int row;
    if (j < 4 * NSEL) {
      const int jp = j / NSEL;
      const int jj = j - jp * NSEL;
      const int p  = jp + (jp >= ii ? 1 : 0);
      row = (s * PIMG + p) * TTOK + indices[p * NSEL + jj];
    } else {
      row = si * TTOK + (j - 4 * NSEL);
    }
    kvrow[j] = (unsigned short)row;
  }
  __syncthreads();  // kvrow ready

  // K slot permutation: slot(kg) = 32w + 8*(l16>>2) + 4*kg + (l16&3).
  // QK^T output element (kg,quad,r) = key 32w+8*quad+4*kg+r == PV A-frag
  // elem j = 4*kg+r at k = 8*quad+j. P stays in registers.
  const int kidx = 32 * wave + ((l16 >> 2) << 3) + (l16 & 3);

  const int va = tid >> 3;        // 0..15: stages rows 4va..4va+3 (pairs 2va,2va+1)
  const int vc = (tid & 7) * 8;   // dim chunk

  bf16x8 kq[2][2], kn[2][2], vs[4], vn[4];
#pragma unroll
  for (int kg = 0; kg < 2; ++kg) {
    const int krow = kvrow[kidx + 4 * kg];
    kq[kg][0] = *(const bf16x8*)&Kf[(size_t)krow * CCH + hc + quad * 8];
    kq[kg][1] = *(const bf16x8*)&Kf[(size_t)krow * CCH + hc + quad * 8 + 32];
  }
#pragma unroll
  for (int e = 0; e < 4; ++e)
    vs[e] = *(const bf16x8*)&Vf[(size_t)kvrow[4 * va + e] * CCH + hc + vc];

  float l_part[4] = {0.f, 0.f, 0.f, 0.f};
  f32x4 oacc[4][4];
#pragma unroll
  for (int n = 0; n < 4; ++n)
#pragma unroll
    for (int dg = 0; dg < 4; ++dg) oacc[n][dg] = (f32x4){0.f, 0.f, 0.f, 0.f};

  for (int kt = 0; kt < KT_TILES; ++kt) {
    // ---- commit staged V tile: key-pairs packed as dwords, swizzled ----
    {
      unsigned int* V32 = (unsigned int*)&Vts[kt & 1][0];
      const unsigned short* q0 = (const unsigned short*)&vs[0];
      const unsigned short* q1 = (const unsigned short*)&vs[1];
      const unsigned short* q2 = (const unsigned short*)&vs[2];
      const unsigned short* q3 = (const unsigned short*)&vs[3];
#pragma unroll
      for (int x = 0; x < 8; ++x) {
        const int sx = (vc >> 1) ^ (x << 2);   // 4*(c^x)
        V32[(vc + x) * 32 + ((2 * va) ^ sx)]     = (unsigned int)q0[x] | ((unsigned int)q1[x] << 16);
        V32[(vc + x) * 32 + ((2 * va + 1) ^ sx)] = (unsigned int)q2[x] | ((unsigned int)q3[x] << 16);
      }
    }

    // ---- prefetch tile kt+1 (x1 across block, one iteration of slack) ----
    if (kt + 1 < KT_TILES) {
      const int kb = (kt + 1) * 64;
#pragma unroll
      for (int kg = 0; kg < 2; ++kg) {
        const int krow = kvrow[kb + kidx + 4 * kg];
        kn[kg][0] = *(const bf16x8*)&Kf[(size_t)krow * CCH + hc + quad * 8];
        kn[kg][1] = *(const bf16x8*)&Kf[(size_t)krow * CCH + hc + quad * 8 + 32];
      }
#pragma unroll
      for (int e = 0; e < 4; ++e)
        vn[e] = *(const bf16x8*)&Vf[(size_t)kvrow[kb + 4 * va + e] * CCH + hc + vc];
    }

    // ---- S^T = K Q^T (wave's 32 keys x all 64 q) + softmax into A-frags ----
    bf16x8 pa[4];
#pragma unroll
    for (int kg = 0; kg < 2; ++kg) {
#pragma unroll
      for (int n = 0; n < 4; ++n) {
        f32x4 z = (f32x4){0.f, 0.f, 0.f, 0.f};
        z = MFMA_BF16(kq[kg][0], aq[n][0], z);
        z = MFMA_BF16(kq[kg][1], aq[n][1], z);
#pragma unroll
        for (int r = 0; r < 4; ++r) {
          // raw v_exp_f32 via builtin (hazards handled); log2e pre-folded
          // into Q scale so exp2(z) == exp(S).
          const float pv = __builtin_amdgcn_exp2f(z[r]);
          l_part[n] += pv;
          pa[n][4 * kg + r] = (bf16_t)pv;
        }
      }
    }

    __syncthreads();  // Vts[kt&1] visible (the ONLY barrier per iteration)

    // ---- O_partial[all 64 q][all 64 d] += P(wave keys) V(wave keys) ----
    const bf16_t* __restrict__ Vb = &Vts[kt & 1][0];
#pragma unroll
    for (int dg = 0; dg < 4; ++dg) {
      const int d  = 16 * dg + l16;
      const int sw = (d & 56) ^ ((d & 7) << 3);
      const bf16x8 vf = *(const bf16x8*)&Vb[d * 64 + ((32 * wave + 8 * quad) ^ sw)];
#pragma unroll
      for (int n = 0; n < 4; ++n)
        oacc[n][dg] = MFMA_BF16(pa[n], vf, oacc[n][dg]);
    }

    // rotate prefetched registers
#pragma unroll
    for (int kg = 0; kg < 2; ++kg) {
      kq[kg][0] = kn[kg][0];
      kq[kg][1] = kn[kg][1];
    }
#pragma unroll
    for (int e = 0; e < 4; ++e) vs[e] = vn[e];
  }

  __syncthreads();  // drain before aliasing kvrow/Vts as scratch

  // ---- merge l partials: 8 per q (2 waves x 4 quads) ----
  float* lred = (float*)kvrow;        // 512 f32 = 2048 B <= 3456
  float* linv = lred + 512;           // 64 f32
#pragma unroll
  for (int n = 0; n < 4; ++n)
    lred[(16 * n + l16) * 8 + 4 * wave + quad] = l_part[n];
  __syncthreads();
  if (tid < 64) {
    float tt = 0.f;
#pragma unroll
    for (int i = 0; i < 8; ++i) tt += lred[tid * 8 + i];
    linv[tid] = 1.f / tt;
  }
  __syncthreads();

  // ---- cross-wave O sum (f32 through dead Vts) + scaled write ----
  float* Osc = (float*)&Vts[0][0];    // 64*64 f32 = 16384 B (exact fit)
  if (wave == 0) {
#pragma unroll
    for (int n = 0; n < 4; ++n)
#pragma unroll
      for (int r = 0; r < 4; ++r) {
        const int q = 16 * n + 4 * quad + r;
#pragma unroll
        for (int dg = 0; dg < 4; ++dg)
          Osc[q * 64 + 16 * dg + l16] = oacc[n][dg][r];
      }
  }
  __syncthreads();
  if (wave == 1) {
#pragma unroll
    for (int n = 0; n < 4; ++n)
#pragma unroll
      for (int r = 0; r < 4; ++r) {
        const int q   = 16 * n + 4 * quad + r;
        const float inv = linv[q];
#pragma unroll
        for (int dg = 0; dg < 4; ++dg) {
          const float val = (Osc[q * 64 + 16 * dg + l16] + oacc[n][dg][r]) * inv;
          Ofull[(size_t)(r0 + q) * CCH + hc + 16 * dg + l16] = (bf16_t)val;
        }
      }
  }
}

}  // namespace

extern "C" void kernel_launch(void* const* d_in, const int* in_sizes, int n_in,
                              void* d_out, int out_size, void* d_ws, size_t ws_size,
                              hipStream_t stream) {
  const float* hs = (const float*)d_in[0];
  const float* Wq = (const float*)d_in[1];
  const float* Wk = (const float*)d_in[2];
  const float* Wv = (const float*)d_in[3];
  const float* Wo = (const float*)d_in[4];
  const float* bo = (const float*)d_in[5];
  const int* indices = (const int*)d_in[6];
  float* out = (float*)d_out;

  // ws layout (bf16): Qf, Kf, Vf, Xb(->Of after qkv gemm), Wqb, Wkb, Wvb, Wob = 72.1 MB
  bf16_t* Qf  = (bf16_t*)d_ws;
  bf16_t* Kf  = Qf + NXE;
  bf16_t* Vf  = Kf + NXE;
  bf16_t* Xb  = Vf + NXE;     // dead after qkv gemm
  bf16_t* Of  = Xb;           // attn output reuses the slot
  bf16_t* Wqb = Xb + NXE;
  bf16_t* Wkb = Wqb + NWE;
  bf16_t* Wvb = Wkb + NWE;
  bf16_t* Wob = Wvb + NWE;

  dim3 g0((NXE + 2047) / 2048, 5);
  cvt_kernel<<<g0, dim3(256), 0, stream>>>(hs, Wq, Wk, Wv, Wo, Xb, Wqb, Wkb, Wvb, Wob);

  // 1D chunk-swizzled grids (45 bm x 10 bn x {3,1} z decoded in-kernel)
  qkv_gemm_kernel<<<dim3(1350), dim3(256), 0, stream>>>(Xb, Wqb, Wkb, Wvb, Qf, Kf, Vf);

  attn_kernel<<<dim3(1800), dim3(128), 0, stream>>>(Qf, Kf, Vf, indices, Of);

  out_gemm_kernel<<<dim3(450), dim3(256), 0, stream>>>(Of, Wob, bo, out);
}